// Round 1
// baseline (768.080 us; speedup 1.0000x reference)
//
#include <hip/hip_runtime.h>
#include <hip/hip_bf16.h>
#include <cstdint>
#include <cstddef>

#define BB 16
#define NN 1024
#define DD 64
#define NHH 4
#define HDD 16
#define KSPLIT 4

// workspace layout (in floats)
#define OFF_Q  0
#define OFF_K  (OFF_Q + BB*NHH*NN*HDD)                 // 1,048,576
#define OFF_V  (OFF_K + BB*NHH*NN*HDD)
#define OFF_L  (OFF_V + BB*NHH*NN*HDD)                 // + KSPLIT*64*1024
#define OFF_AT (OFF_L + KSPLIT*BB*NHH*NN)
#define OFF_PM (OFF_AT + (size_t)KSPLIT*BB*NHH*NN*HDD) // + 1024

// ---------------------------------------------------------------------------
// K1: patch means (5x5 zero-padded mean) + Q/K/V projections.
// 4 points per block (one per wave); lane = channel. Coords are per-point
// uniform -> bounds branches are wave-uniform (no divergence).
__global__ __launch_bounds__(256) void k_pf_qkv(
    const float* __restrict__ desc, const float* __restrict__ fm,
    const int* __restrict__ coords,
    const float* __restrict__ Wq, const float* __restrict__ bq,
    const float* __restrict__ Wk, const float* __restrict__ bk,
    const float* __restrict__ Wv, const float* __restrict__ bv,
    float* __restrict__ Q, float* __restrict__ K, float* __restrict__ V)
{
    int w   = threadIdx.x >> 6;          // wave in block
    int c   = threadIdx.x & 63;          // channel
    int pid = blockIdx.x * 4 + w;        // b*N+n
    int b   = pid >> 10;
    int n   = pid & 1023;

    __shared__ float spf[4][64];
    __shared__ float sd[4][64];

    int y = coords[pid * 2 + 0];
    int x = coords[pid * 2 + 1];

    const float* fmc = fm + ((size_t)(b * 64 + c) << 16);   // channel plane 256x256
    float s = 0.f;
    #pragma unroll
    for (int dy = -2; dy <= 2; ++dy) {
        int yy = y + dy;
        if ((unsigned)yy < 256u) {
            const float* row = fmc + yy * 256;
            #pragma unroll
            for (int dx = -2; dx <= 2; ++dx) {
                int xx = x + dx;
                if ((unsigned)xx < 256u) s += row[xx];
            }
        }
    }
    spf[w][c] = s * 0.04f;                        // /25
    sd[w][c]  = desc[(size_t)pid * 64 + c];
    __syncthreads();

    float aq = bq[c], ak = bk[c], av = bv[c];
    #pragma unroll 8
    for (int i = 0; i < 64; ++i) {
        float xd = sd[w][i];
        float xp = spf[w][i];
        aq = fmaf(xd, Wq[i * 64 + c], aq);
        ak = fmaf(xp, Wk[i * 64 + c], ak);
        av = fmaf(xp, Wv[i * 64 + c], av);
    }
    int h = c >> 4, d = c & 15;
    size_t o = (((size_t)b * 4 + h) * 1024 + n) * 16 + d;   // (B,NH,N,hd)
    Q[o] = aq; K[o] = ak; V[o] = av;
}

// ---------------------------------------------------------------------------
// K2: pm1[b][c] = 1 + (pose_embed @ Wp + bp)
__global__ __launch_bounds__(64) void k_pose(
    const float* __restrict__ pe, const float* __restrict__ Wp,
    const float* __restrict__ bp, float* __restrict__ pm1)
{
    int b = blockIdx.x, c = threadIdx.x;
    __shared__ float sp[64];
    sp[c] = pe[b * 64 + c];
    __syncthreads();
    float acc = bp[c];
    #pragma unroll 8
    for (int i = 0; i < 64; ++i) acc = fmaf(sp[i], Wp[i * 64 + c], acc);
    pm1[b * 64 + c] = 1.f + acc;
}

// ---------------------------------------------------------------------------
// K3: attention with shift-free softmax, split-K over keys.
// One lane = one query row; K/V rows are wave-uniform broadcast loads.
// grid = B*NH*16*KSPLIT blocks of 64.
__global__ __launch_bounds__(64) void k_attn(
    const float* __restrict__ Q, const float* __restrict__ K,
    const float* __restrict__ V,
    float* __restrict__ lpart, float* __restrict__ apart)
{
    int idx = blockIdx.x;
    int s  = idx & (KSPLIT - 1);
    int qt = (idx >> 2) & 15;
    int bh = idx >> 6;                    // b*4+h, 0..63
    int r  = qt * 64 + threadIdx.x;

    const float4* q4 = (const float4*)(Q + (((size_t)bh * 1024 + r) << 4));
    float4 qa = q4[0], qb = q4[1], qc = q4[2], qd = q4[3];

    float4 A0 = {0,0,0,0}, A1 = {0,0,0,0}, A2 = {0,0,0,0}, A3 = {0,0,0,0};
    float l = 0.f;

    const float4* Kb = (const float4*)(K + ((size_t)bh << 14));
    const float4* Vb = (const float4*)(V + ((size_t)bh << 14));

    int m0 = s << 8;
    #pragma unroll 2
    for (int m = m0; m < m0 + 256; ++m) {
        float4 ka = Kb[m*4+0], kb = Kb[m*4+1], kc = Kb[m*4+2], kd = Kb[m*4+3];
        float4 va = Vb[m*4+0], vb = Vb[m*4+1], vc = Vb[m*4+2], vd = Vb[m*4+3];
        float sc = qa.x*ka.x + qa.y*ka.y + qa.z*ka.z + qa.w*ka.w
                 + qb.x*kb.x + qb.y*kb.y + qb.z*kb.z + qb.w*kb.w
                 + qc.x*kc.x + qc.y*kc.y + qc.z*kc.z + qc.w*kc.w
                 + qd.x*kd.x + qd.y*kd.y + qd.z*kd.z + qd.w*kd.w;
        float p = __expf(sc * 0.25f);     // scores bounded ~|3|: no max-shift needed
        l += p;
        A0.x = fmaf(p, va.x, A0.x); A0.y = fmaf(p, va.y, A0.y);
        A0.z = fmaf(p, va.z, A0.z); A0.w = fmaf(p, va.w, A0.w);
        A1.x = fmaf(p, vb.x, A1.x); A1.y = fmaf(p, vb.y, A1.y);
        A1.z = fmaf(p, vb.z, A1.z); A1.w = fmaf(p, vb.w, A1.w);
        A2.x = fmaf(p, vc.x, A2.x); A2.y = fmaf(p, vc.y, A2.y);
        A2.z = fmaf(p, vc.z, A2.z); A2.w = fmaf(p, vc.w, A2.w);
        A3.x = fmaf(p, vd.x, A3.x); A3.y = fmaf(p, vd.y, A3.y);
        A3.z = fmaf(p, vd.z, A3.z); A3.w = fmaf(p, vd.w, A3.w);
    }

    size_t ro = (size_t)(s * 64 + bh) * 1024 + r;
    lpart[ro] = l;
    float4* ap = (float4*)(apart + (ro << 4));
    ap[0] = A0; ap[1] = A1; ap[2] = A2; ap[3] = A3;
}

// ---------------------------------------------------------------------------
// K4: combine split-K partials, softmax divide, pose modulation, @ Wo + bo.
// 4 points per block (one per wave).
__global__ __launch_bounds__(256) void k_out(
    const float* __restrict__ lpart, const float* __restrict__ apart,
    const float* __restrict__ pm1, const float* __restrict__ Wo,
    const float* __restrict__ bo, float* __restrict__ out)
{
    int w   = threadIdx.x >> 6;
    int c   = threadIdx.x & 63;
    int pid = blockIdx.x * 4 + w;
    int b   = pid >> 10;
    int n   = pid & 1023;
    int h   = c >> 4, d = c & 15;
    int bh  = b * 4 + h;

    __shared__ float sf[4][64];

    float a = 0.f, ls = 0.f;
    #pragma unroll
    for (int s = 0; s < KSPLIT; ++s) {
        size_t ro = (size_t)(s * 64 + bh) * 1024 + n;
        a  += apart[(ro << 4) + d];
        ls += lpart[ro];
    }
    sf[w][c] = (a / ls) * pm1[b * 64 + c];
    __syncthreads();

    float acc = bo[c];
    #pragma unroll 8
    for (int i = 0; i < 64; ++i) acc = fmaf(sf[w][i], Wo[i * 64 + c], acc);
    out[(size_t)pid * 64 + c] = acc;
}

// ---------------------------------------------------------------------------
extern "C" void kernel_launch(void* const* d_in, const int* in_sizes, int n_in,
                              void* d_out, int out_size, void* d_ws, size_t ws_size,
                              hipStream_t stream)
{
    const float* desc = (const float*)d_in[0];
    const float* fm   = (const float*)d_in[1];
    const int*   crd  = (const int*)  d_in[2];
    const float* pe   = (const float*)d_in[3];
    const float* Wq   = (const float*)d_in[4];
    const float* bq   = (const float*)d_in[5];
    const float* Wk   = (const float*)d_in[6];
    const float* bk   = (const float*)d_in[7];
    const float* Wv   = (const float*)d_in[8];
    const float* bv   = (const float*)d_in[9];
    const float* Wp   = (const float*)d_in[10];
    const float* bp   = (const float*)d_in[11];
    const float* Wo   = (const float*)d_in[12];
    const float* bo   = (const float*)d_in[13];
    float* out = (float*)d_out;

    float* ws    = (float*)d_ws;
    float* Qb    = ws + OFF_Q;
    float* Kb    = ws + OFF_K;
    float* Vb    = ws + OFF_V;
    float* lpart = ws + OFF_L;
    float* apart = ws + OFF_AT;
    float* pm1   = ws + OFF_PM;

    // K1: patch means + QKV. 16384 points, 4/block.
    hipLaunchKernelGGL(k_pf_qkv, dim3(BB * NN / 4), dim3(256), 0, stream,
                       desc, fm, crd, Wq, bq, Wk, bk, Wv, bv, Qb, Kb, Vb);
    // K2: pose modulation vector.
    hipLaunchKernelGGL(k_pose, dim3(BB), dim3(64), 0, stream, pe, Wp, bp, pm1);
    // K3: attention, split-K.
    hipLaunchKernelGGL(k_attn, dim3(BB * NHH * 16 * KSPLIT), dim3(64), 0, stream,
                       Qb, Kb, Vb, lpart, apart);
    // K4: combine + pose scale + output projection.
    hipLaunchKernelGGL(k_out, dim3(BB * NN / 4), dim3(256), 0, stream,
                       lpart, apart, pm1, Wo, bo, out);
}